// Round 11
// baseline (204.302 us; speedup 1.0000x reference)
//
#include <hip/hip_runtime.h>

// Problem constants
#define S_DIM 8192
#define K_DIM 1024
#define RO_DIM 4096
#define O_DIM 64
#define SO (S_DIM * O_DIM)
#define NSLICE 16  // N/256 partial slices

typedef __attribute__((ext_vector_type(8))) __bf16 bf16x8;
typedef __attribute__((ext_vector_type(4))) float floatx4;
typedef __attribute__((ext_vector_type(4))) unsigned short ushx4;
typedef __attribute__((ext_vector_type(8))) unsigned short ushx8;
typedef __attribute__((address_space(3))) const unsigned short* ldsp;

__device__ inline unsigned short f2bf(float f) {
  unsigned u = __builtin_bit_cast(unsigned, f);
  u += 0x7fff + ((u >> 16) & 1);  // round-to-nearest-even
  return (unsigned short)(u >> 16);
}
__device__ inline float bf2f(unsigned short h) {
  unsigned u = ((unsigned)h) << 16;
  return __builtin_bit_cast(float, u);
}

// ---------------------------------------------------------------- cast X,W -> bf16
// Separate kernel (R8: fusing it makes the GEMM re-fetch fp32 ~3.3x).
__global__ __launch_bounds__(256) void cast_kernel(const float* __restrict__ X,
                                                   const float* __restrict__ W,
                                                   unsigned short* __restrict__ Xb,
                                                   unsigned short* __restrict__ Wb) {
  const int NX4 = (S_DIM * K_DIM) / 4;
#pragma unroll
  for (int i = 0; i < 4; ++i) {
    int g = blockIdx.x * 1024 + i * 256 + threadIdx.x;
    float4 v;
    unsigned short* dst;
    if (g < NX4) {
      v = ((const float4*)X)[g];
      dst = Xb + (size_t)g * 4;
    } else {
      int j = g - NX4;
      v = ((const float4*)W)[j];
      dst = Wb + (size_t)j * 4;
    }
    ushx4 o;
    o.x = f2bf(v.x); o.y = f2bf(v.y); o.z = f2bf(v.z); o.w = f2bf(v.w);
    *(ushx4*)dst = o;
  }
}

// ---------------------------------------------------------------- asm LDS reads (invisible to barrier drain)
// 4x ds_read_b128 from one base, stride 2048B (frag rows 16 apart in a [*][64] tile).
__device__ __forceinline__ void rd4lo(bf16x8& f0, bf16x8& f1, bf16x8& f2, bf16x8& f3, ldsp b) {
  asm volatile("ds_read_b128 %0, %4 offset:0\n\t"
               "ds_read_b128 %1, %4 offset:2048\n\t"
               "ds_read_b128 %2, %4 offset:4096\n\t"
               "ds_read_b128 %3, %4 offset:6144"
               : "=&v"(f0), "=&v"(f1), "=&v"(f2), "=&v"(f3) : "v"(b) : "memory");
}
__device__ __forceinline__ void rd4hi(bf16x8& f0, bf16x8& f1, bf16x8& f2, bf16x8& f3, ldsp b) {
  asm volatile("ds_read_b128 %0, %4 offset:8192\n\t"
               "ds_read_b128 %1, %4 offset:10240\n\t"
               "ds_read_b128 %2, %4 offset:12288\n\t"
               "ds_read_b128 %3, %4 offset:14336"
               : "=&v"(f0), "=&v"(f1), "=&v"(f2), "=&v"(f3) : "v"(b) : "memory");
}

// counted waits; sched_barrier(0) after each (rule #18: hipcc hoists reg-only
// MFMA past inline-asm waitcnt without it).
#define LGKM0() { asm volatile("s_waitcnt lgkmcnt(0)" ::: "memory"); __builtin_amdgcn_sched_barrier(0); }
#define LGKM8() { asm volatile("s_waitcnt lgkmcnt(8)" ::: "memory"); __builtin_amdgcn_sched_barrier(0); }
#define VMCNT0() { asm volatile("s_waitcnt vmcnt(0)" ::: "memory"); }
#define SB0() __builtin_amdgcn_sched_barrier(0)
#define BAR() __builtin_amdgcn_s_barrier()

template <int MB>
__device__ __forceinline__ void mf32(floatx4 (&acc)[8][4], const bf16x8 (&af)[4][2],
                                     const bf16x8 (&bf)[4][2]) {
  __builtin_amdgcn_s_setprio(1);
#pragma unroll
  for (int ks = 0; ks < 2; ++ks)
#pragma unroll
    for (int m = 0; m < 4; ++m)
#pragma unroll
      for (int n = 0; n < 4; ++n)
        acc[MB + m][n] = __builtin_amdgcn_mfma_f32_16x16x32_bf16(
            af[m][ks], bf[n][ks], acc[MB + m][n], 0, 0, 0);
  __builtin_amdgcn_s_setprio(0);
}

// ---------------------------------------------------------------- 256x256 GEMM, cross-barrier asm pipeline
// R11: the serialization killer was that compiler-visible ds_reads get lgkm-
// DRAINED at every barrier (m97), so MFMA never overlapped LDS reads. Reads are
// now inline-asm (counter-managed by hand), 2 phases + ONE barrier per k-tile:
//  P0: issue asm reads B(kt)[8]+A1(kt)[8]; lgkmcnt(8) -> A0,B ready, A1 in
//      flight; MFMA A0xB (32) hides A1's drain.
//  P1: lgkmcnt(0) (A1, already drained); vmcnt(0) (tile kt+1's stages, issued
//      one full tile ago ~1000cy slack); BAR; stage tile kt+2 -> CURRENT buffer
//      (all reads of it provably retired pre-BAR: B+A0 at P0's lgkmcnt(8), A1
//      at P1's lgkmcnt(0), per wave, before each wave's BAR arrival); issue asm
//      reads A0(kt+1)[8] from the OTHER buffer (certified by vmcnt+BAR); MFMA
//      A1xB (32) hides their drain.
// Invariant at P0 entry: exactly 8 lgkm outstanding (A0 of this tile).
// B regs single-set: last MFMA use at P1 precedes next P0's reads in program
// order. Tail: kt=14 -> no stage; kt=15 -> no VMCNT/BAR/reads.
// Kept: XOR k-chunk swizzle, XCD remap (XCD x owns bx {2x,2x+1}), k-outermost
// MFMA, setprio, epilogue, 3-kernel split (cross-block comm is poison: R4/R5/R9).

__global__ __launch_bounds__(512, 2) void gemm_kernel(const unsigned short* __restrict__ Xb,
                                                      const unsigned short* __restrict__ Wb,
                                                      const float* __restrict__ bias,
                                                      const float* __restrict__ lam,
                                                      unsigned short* __restrict__ partial) {
  __shared__ __align__(16) unsigned char smem[135168];  // 128KB buffers + 4KB lamsh
  unsigned short* sm = (unsigned short*)smem;
  float* lamsh = (float*)(smem + 131072);  // [256][4]
  auto lds3 = (__attribute__((address_space(3))) unsigned short*)smem;

  const int t = threadIdx.x;
  const int lane = t & 63;
  const int w = t >> 6;
  const int wm = w >> 2;   // M half: rows wm*128..+127
  const int wn = w & 3;    // N quarter = rule index within block
  const int quad = lane >> 4;
  const int l16 = lane & 15;

  // XCD-locality remap: hw XCD = id%8. XCD x gets bx in {2x,2x+1}.
  int id = blockIdx.y * 16 + blockIdx.x;
  int x = id & 7;
  int j = id >> 3;               // 0..63
  const int bx = 2 * x + (j & 1);
  const int by = j >> 1;         // 0..31
  const int gm0 = by * 256;
  const int gn0 = bx * 256;

  // staging per-thread constants (gcc = chunk ^ (row&7) is thread-invariant)
  const int rowt = t >> 3;                       // 0..63
  const int gcc = (t & 7) ^ (rowt & 7);
  const size_t goff = (size_t)rowt * K_DIM + (size_t)gcc * 8;
  const unsigned short* Abase = Xb + (size_t)gm0 * K_DIM;
  const unsigned short* Bbase = Wb + (size_t)gn0 * K_DIM;

  auto STAGE = [&](const unsigned short* gbase, int half, int ktile, int slotOff) {
#pragma unroll
    for (int jj = 0; jj < 2; ++jj) {
      const unsigned short* src =
          gbase + (size_t)(half * 128 + jj * 64) * K_DIM + ktile * 64 + goff;
      __builtin_amdgcn_global_load_lds(
          (const __attribute__((address_space(1))) void*)src,
          (__attribute__((address_space(3))) void*)(sm + slotOff + jj * 4096 + t * 8),
          16, 0, 0);
    }
  };

  // hoist bias/lam values BEFORE stages (their vm loads stay older than all
  // staging ops; "memory"-clobbered asm waits pin them above VMCNT0)
  float bv[4];
#pragma unroll
  for (int ni = 0; ni < 4; ++ni) bv[ni] = bias[gn0 + wn * 64 + ni * 16 + l16];
  float lv0 = lam[(size_t)(gm0 + (t >> 2)) * 64 + bx * 4 + (t & 3)];
  int i2 = t + 512;
  float lv1 = lam[(size_t)(gm0 + (i2 >> 2)) * 64 + bx * 4 + (i2 & 3)];

  // prologue: stage tile0 -> buf0, tile1 -> buf1 (16 gloads)
  STAGE(Abase, 0, 0, 0);
  STAGE(Abase, 1, 0, 8192);
  STAGE(Bbase, 0, 0, 16384);
  STAGE(Bbase, 1, 0, 24576);
  STAGE(Abase, 0, 1, 32768 + 0);
  STAGE(Abase, 1, 1, 32768 + 8192);
  STAGE(Bbase, 0, 1, 32768 + 16384);
  STAGE(Bbase, 1, 1, 32768 + 24576);
  lamsh[t] = lv0;
  lamsh[t + 512] = lv1;
  VMCNT0();
  LGKM0();
  BAR();

  floatx4 acc[8][4];
#pragma unroll
  for (int ni = 0; ni < 4; ++ni)
#pragma unroll
    for (int mi = 0; mi < 8; ++mi) acc[mi][ni] = (floatx4){bv[ni], bv[ni], bv[ni], bv[ni]};

  const int cA0 = ((quad) ^ (l16 & 7)) * 8;        // k-chunk ks=0, swizzled (elems)
  const int cA1 = ((4 + quad) ^ (l16 & 7)) * 8;    // k-chunk ks=1, swizzled

  const int aoff = wm * 8192 + l16 * 64;
  const int boff = 16384 + wn * 4096 + l16 * 64;
  ldsp A00 = lds3 + aoff + cA0;            // buf0 A, ks0
  ldsp A01 = lds3 + aoff + cA1;            // buf0 A, ks1
  ldsp B00 = lds3 + boff + cA0;
  ldsp B01 = lds3 + boff + cA1;
  ldsp A10 = A00 + 32768;                  // buf1
  ldsp A11 = A01 + 32768;
  ldsp B10 = B00 + 32768;
  ldsp B11 = B01 + 32768;

  bf16x8 af0[4][2], af1[4][2], bfr[4][2];

  // prologue reads: A0 of tile0 (establishes the 8-outstanding invariant)
  rd4lo(af0[0][0], af0[1][0], af0[2][0], af0[3][0], A00);
  rd4lo(af0[0][1], af0[1][1], af0[2][1], af0[3][1], A01);

  auto TILE = [&](int kt, ldsp aC0, ldsp aC1, ldsp bC0, ldsp bC1,
                  ldsp aN0, ldsp aN1, int bufC) {
    // ---- P0: issue B + A1 (16 reads); wait A0,B; MFMA A0xB hides A1 drain
    rd4lo(bfr[0][0], bfr[1][0], bfr[2][0], bfr[3][0], bC0);
    rd4lo(bfr[0][1], bfr[1][1], bfr[2][1], bfr[3][1], bC1);
    rd4hi(af1[0][0], af1[1][0], af1[2][0], af1[3][0], aC0);
    rd4hi(af1[0][1], af1[1][1], af1[2][1], af1[3][1], aC1);
    LGKM8();
    mf32<0>(acc, af0, bfr);
    // ---- P1: A1 ready; certify next buffer; stage kt+2; prefetch next A0
    LGKM0();
    if (kt < 15) {
      VMCNT0();
      BAR();
      if (kt < 14) {
        STAGE(Abase, 0, kt + 2, bufC + 0);
        STAGE(Abase, 1, kt + 2, bufC + 8192);
        STAGE(Bbase, 0, kt + 2, bufC + 16384);
        STAGE(Bbase, 1, kt + 2, bufC + 24576);
      }
      rd4lo(af0[0][0], af0[1][0], af0[2][0], af0[3][0], aN0);
      rd4lo(af0[0][1], af0[1][1], af0[2][1], af0[3][1], aN1);
      SB0();
    }
    mf32<4>(acc, af1, bfr);
  };

  for (int k2 = 0; k2 < 16; k2 += 2) {
    TILE(k2, A00, A01, B00, B01, A10, A11, 0);
    TILE(k2 + 1, A10, A11, B10, B11, A00, A01, 32768);
  }

  // ---- epilogue: rule-weighted sigmoid -> LDS (bf16), 4-rule in-block reduce,
  // bf16 partial slice write (contention-free; reduce kernel finishes).
  __syncthreads();
  {
    unsigned short* yreg = sm + wn * 16384;  // [256][64], col-chunk ^= quad (banks)
#pragma unroll
    for (int mi = 0; mi < 8; ++mi) {
#pragma unroll
      for (int r = 0; r < 4; ++r) {
        int row = wm * 128 + mi * 16 + quad * 4 + r;
        float lamv = lamsh[row * 4 + wn];
#pragma unroll
        for (int ni = 0; ni < 4; ++ni) {
          float sg = 1.f / (1.f + __expf(-acc[mi][ni][r]));
          yreg[row * 64 + ((ni ^ quad) * 16) + l16] = f2bf(lamv * sg);
        }
      }
    }
  }
  __syncthreads();
  {
    unsigned short* pb = partial + (size_t)bx * SO + (size_t)gm0 * 64;
#pragma unroll
    for (int g = 0; g < 4; ++g) {
      int idx = g * 4096 + t * 8;  // lane-contiguous
      int row = idx >> 6;
      int c = idx & 63;
      int phys = row * 64 + ((((c >> 4) ^ ((row >> 2) & 3))) << 4) + (c & 15);
      float s[8];
#pragma unroll
      for (int jj = 0; jj < 8; ++jj) s[jj] = 0.f;
#pragma unroll
      for (int q = 0; q < 4; ++q) {
        ushx8 v = *(const ushx8*)(sm + q * 16384 + phys);
#pragma unroll
        for (int jj = 0; jj < 8; ++jj) s[jj] += bf2f(v[jj]);
      }
      ushx8 o;
#pragma unroll
      for (int jj = 0; jj < 8; ++jj) o[jj] = f2bf(s[jj]);
      *(ushx8*)(pb + idx) = o;
    }
  }
}

// ---------------------------------------------------------------- final reduce over 16 N-tiles
__global__ __launch_bounds__(256) void reduce_kernel(const unsigned short* __restrict__ partial,
                                                     float* __restrict__ Y) {
  int i4 = blockIdx.x * 256 + threadIdx.x;
  float s0 = 0.f, s1 = 0.f, s2 = 0.f, s3 = 0.f;
#pragma unroll
  for (int c = 0; c < NSLICE; ++c) {
    ushx4 v = ((const ushx4*)(partial + (size_t)c * SO))[i4];
    s0 += bf2f(v.x); s1 += bf2f(v.y); s2 += bf2f(v.z); s3 += bf2f(v.w);
  }
  ((float4*)Y)[i4] = (float4){s0, s1, s2, s3};
}

extern "C" void kernel_launch(void* const* d_in, const int* in_sizes, int n_in,
                              void* d_out, int out_size, void* d_ws, size_t ws_size,
                              hipStream_t stream) {
  const float* X = (const float*)d_in[0];     // [8192,1024]
  const float* W = (const float*)d_in[1];     // [4096,1024]
  const float* b = (const float*)d_in[2];     // [4096]
  const float* lam = (const float*)d_in[3];   // [8192,64]
  float* Y = (float*)d_out;                   // [8192,64]

  unsigned short* Xb = (unsigned short*)d_ws;                 // 16 MB
  unsigned short* Wb = Xb + (size_t)S_DIM * K_DIM;            // 8 MB
  unsigned short* partial = Wb + (size_t)RO_DIM * K_DIM;      // 16 slices x 1 MB

  int nCast = ((S_DIM + RO_DIM) * K_DIM / 4) / 1024;  // 3072 blocks
  cast_kernel<<<nCast, 256, 0, stream>>>(X, W, Xb, Wb);

  dim3 g(RO_DIM / 256, S_DIM / 256);  // (16, 32) = 512 blocks, 512 threads
  gemm_kernel<<<g, 512, 0, stream>>>(Xb, Wb, b, lam, partial);

  reduce_kernel<<<SO / 1024, 256, 0, stream>>>(partial, Y);
}